// Round 1
// baseline (1030.721 us; speedup 1.0000x reference)
//
#include <hip/hip_runtime.h>

namespace {

constexpr int NBLK = 4 * 64 * 64;       // 16384 columns per branch
constexpr size_t RSTR = 64 * 64 * 32;   // stride over s1 in floats

// ---------------- shared memory layouts (float offsets) ----------------
// kz (z-branch): total 8192 floats = 32 KB
constexpr int ZS_XS = 0;      // x slab [z][i]        2048
constexpr int ZS_TF = 2048;   // fwd trig f4 [z][m2]  2048
constexpr int ZS_TI = 4096;   // inv trig f2 [z][m]   2048
constexpr int ZS_FS = 6144;   // F f2 [16][32]        1024
constexpr int ZS_PS = 7168;   // P f2 [16][32]        1024
constexpr int ZS_TOT = 8192;

// kx (x-branch + FFN): total 12704 floats ~= 49.6 KB (regions reused over time)
constexpr int XS_H  = 0;      // h [64][68]           4352 (overlays XS/TF, both dead)
constexpr int XS_XS = 0;      // x slab [s1][i]       2048 (dead after F)
constexpr int XS_TF = 2048;   // fwd trig             2048 (dead after F)
constexpr int XS_TI = 4352;   // inv trig             2048 (dead after INV)
constexpr int XS_FS = 6400;   // F                    1024 (dead after MIX)
constexpr int XS_PS = 7424;   // P                    1024 (dead after INV)
constexpr int XS_W1 = 6400;   // w1 [32][64]          2048 (staged after INV)
constexpr int XS_W2 = 8448;   // w2 [64][32]          2048
constexpr int XS_YS = 10496;  // y+xx [64][33]        2112
constexpr int XS_B1 = 12608;  // 64
constexpr int XS_B2 = 12672;  // 32
constexpr int XS_TOT = 12704;

__device__ __forceinline__ float f4get(const float4& v, int u) {
  return u == 0 ? v.x : (u == 1 ? v.y : (u == 2 ? v.z : v.w));
}

// Build trig tables in LDS. Folds rfft/irfft 'ortho' norms and the
// irfft hermitian handling (Im(DC) dropped; factor 2 for m>=1).
__device__ __forceinline__ void build_tables(float* __restrict__ tf,
                                             float* __restrict__ ti, int t) {
  // forward [z][m2] float4 = (cos(2pi*(2m2)z/64)/8, -sin/8, cos(2pi*(2m2+1)z/64)/8, -sin/8)
  for (int e = t; e < 512; e += 256) {
    int z = e >> 3, m2 = e & 7;
    float s0, c0, s1, c1;
    sincospif((float)((2 * m2) * z) * (1.0f / 32.0f), &s0, &c0);
    sincospif((float)((2 * m2 + 1) * z) * (1.0f / 32.0f), &s1, &c1);
    reinterpret_cast<float4*>(tf)[e] =
        make_float4(0.125f * c0, -0.125f * s0, 0.125f * c1, -0.125f * s1);
  }
  // inverse [z][m] float2 = (sc_m*cos(2pi m z/64), -sc_m*sin), sc_0=1/8 else 1/4
  for (int e = t; e < 1024; e += 256) {
    int z = e >> 4, m = e & 15;
    float s, c;
    sincospif((float)(m * z) * (1.0f / 32.0f), &s, &c);
    float sc = (m == 0) ? 0.125f : 0.25f;
    reinterpret_cast<float2*>(ti)[e] = make_float2(sc * c, -sc * s);
  }
}

// F[m][i] = sum_z x[z][i] * E[m][z]  (complex, E has 1/8 and -sin folded)
__device__ __forceinline__ void phase_forward(const float* __restrict__ sm, int xs_off,
                                              int tf_off, float* __restrict__ fs, int t) {
  int i = t & 31, m2 = t >> 5;
  const float4* tf = reinterpret_cast<const float4*>(sm + tf_off);
  float re0 = 0.f, im0 = 0.f, re1 = 0.f, im1 = 0.f;
#pragma unroll
  for (int z = 0; z < 64; ++z) {
    float xv = sm[xs_off + z * 32 + i];
    float4 tv = tf[z * 8 + m2];
    re0 = fmaf(xv, tv.x, re0);
    im0 = fmaf(xv, tv.y, im0);
    re1 = fmaf(xv, tv.z, re1);
    im1 = fmaf(xv, tv.w, im1);
  }
  float2* F2 = reinterpret_cast<float2*>(fs);
  F2[(2 * m2) * 32 + i] = make_float2(re0, im0);
  F2[(2 * m2 + 1) * 32 + i] = make_float2(re1, im1);
}

// P[m][o] = sum_i F[m][i] * W[i][o][m]   (complex; W raw layout [i][o][m][2])
__device__ __forceinline__ void phase_mix(const float* __restrict__ fs,
                                          const float* __restrict__ wraw,
                                          float* __restrict__ ps, int t) {
  int o = t & 31, m2 = t >> 5;
  const float2* F2 = reinterpret_cast<const float2*>(fs);
  const float2* W2 = reinterpret_cast<const float2*>(wraw);
  float pr0 = 0.f, pi0 = 0.f, pr1 = 0.f, pi1 = 0.f;
#pragma unroll
  for (int i = 0; i < 32; ++i) {
    float2 f0 = F2[m2 * 32 + i];
    float2 f1 = F2[(m2 + 8) * 32 + i];
    float2 w0 = W2[(i * 32 + o) * 16 + m2];
    float2 w1 = W2[(i * 32 + o) * 16 + m2 + 8];
    pr0 = fmaf(f0.x, w0.x, pr0); pr0 = fmaf(f0.y, -w0.y, pr0);
    pi0 = fmaf(f0.x, w0.y, pi0); pi0 = fmaf(f0.y,  w0.x, pi0);
    pr1 = fmaf(f1.x, w1.x, pr1); pr1 = fmaf(f1.y, -w1.y, pr1);
    pi1 = fmaf(f1.x, w1.y, pi1); pi1 = fmaf(f1.y,  w1.x, pi1);
  }
  float2* P2 = reinterpret_cast<float2*>(ps);
  P2[m2 * 32 + o] = make_float2(pr0, pi0);
  P2[(m2 + 8) * 32 + o] = make_float2(pr1, pi1);
}

// ---------------- z-branch: contiguous column along s3 ----------------
__global__ __launch_bounds__(256) void kz(const float* __restrict__ x,
                                          const float* __restrict__ wz,
                                          float* __restrict__ y) {
  __shared__ __align__(16) float sm[ZS_TOT];
  const int t = threadIdx.x;
  const int p = blockIdx.x;                   // (b*64+s1)*64+s2
  const size_t base = (size_t)p * 2048;

  build_tables(sm + ZS_TF, sm + ZS_TI, t);
  {
    const float4* xg = reinterpret_cast<const float4*>(x + base);
    float4* xs = reinterpret_cast<float4*>(sm + ZS_XS);
    xs[t] = xg[t];
    xs[t + 256] = xg[t + 256];
  }
  __syncthreads();

  phase_forward(sm, ZS_XS, ZS_TF, sm + ZS_FS, t);
  __syncthreads();

  phase_mix(sm + ZS_FS, wz, sm + ZS_PS, t);
  __syncthreads();

  {  // inverse + direct store (y goes into d_out)
    int o = t & 31, z0 = t >> 5;
    const float2* P2 = reinterpret_cast<const float2*>(sm + ZS_PS);
    const float2* ti = reinterpret_cast<const float2*>(sm + ZS_TI);
    float pr[16], pi[16];
#pragma unroll
    for (int m = 0; m < 16; ++m) { float2 v = P2[m * 32 + o]; pr[m] = v.x; pi[m] = v.y; }
#pragma unroll
    for (int k = 0; k < 8; ++k) {
      int z = z0 + 8 * k;
      float acc = 0.f;
#pragma unroll
      for (int m = 0; m < 16; ++m) {
        float2 tv = ti[z * 16 + m];
        acc = fmaf(tv.x, pr[m], acc);
        acc = fmaf(tv.y, pi[m], acc);
      }
      y[base + z * 32 + o] = acc;
    }
  }
}

// ------- x-branch (column along s1) + add z-branch + FFN, overwrites d_out -------
__global__ __launch_bounds__(256) void kx(const float* __restrict__ x,
                                          const float* __restrict__ wx,
                                          const float* __restrict__ w1,
                                          const float* __restrict__ b1,
                                          const float* __restrict__ w2,
                                          const float* __restrict__ b2,
                                          float* out) {
  __shared__ __align__(16) float sm[XS_TOT];
  const int t = threadIdx.x;
  int p = blockIdx.x;
  p = (p & 7) * 2048 + (p >> 3);              // XCD-bijective swizzle (16384 % 8 == 0)
  const int b = p >> 12, yy = (p >> 6) & 63, zz = p & 63;
  const size_t gbase = (size_t)b * 8388608 + (size_t)yy * 2048 + (size_t)zz * 32;

  build_tables(sm + XS_TF, sm + XS_TI, t);
  {  // gather slab xs[s1][i]; rows are 128B contiguous, stride RSTR
    float4* xs = reinterpret_cast<float4*>(sm + XS_XS);
#pragma unroll
    for (int g = t; g < 512; g += 256) {
      int row = g >> 3, slot = g & 7;
      xs[g] = *reinterpret_cast<const float4*>(x + gbase + (size_t)row * RSTR + slot * 4);
    }
  }
  __syncthreads();

  phase_forward(sm, XS_XS, XS_TF, sm + XS_FS, t);
  __syncthreads();

  phase_mix(sm + XS_FS, wx, sm + XS_PS, t);
  __syncthreads();

  {  // inverse + add z-branch result (read from d_out) -> ys LDS
    int o = t & 31, z0 = t >> 5;
    const float2* P2 = reinterpret_cast<const float2*>(sm + XS_PS);
    const float2* ti = reinterpret_cast<const float2*>(sm + XS_TI);
    float pr[16], pi[16];
#pragma unroll
    for (int m = 0; m < 16; ++m) { float2 v = P2[m * 32 + o]; pr[m] = v.x; pi[m] = v.y; }
#pragma unroll
    for (int k = 0; k < 8; ++k) {
      int z = z0 + 8 * k;  // z == s1 here
      float acc = out[gbase + (size_t)z * RSTR + o];   // z-branch partial
#pragma unroll
      for (int m = 0; m < 16; ++m) {
        float2 tv = ti[z * 16 + m];
        acc = fmaf(tv.x, pr[m], acc);
        acc = fmaf(tv.y, pi[m], acc);
      }
      sm[XS_YS + z * 33 + o] = acc;
    }
  }
  __syncthreads();

  {  // stage FFN weights (into regions dead after INV)
    float4* w1s = reinterpret_cast<float4*>(sm + XS_W1);
    float4* w2s = reinterpret_cast<float4*>(sm + XS_W2);
    const float4* w1g = reinterpret_cast<const float4*>(w1);
    const float4* w2g = reinterpret_cast<const float4*>(w2);
    w1s[t] = w1g[t]; w1s[t + 256] = w1g[t + 256];
    w2s[t] = w2g[t]; w2s[t + 256] = w2g[t + 256];
    if (t < 64) sm[XS_B1 + t] = b1[t];
    if (t < 32) sm[XS_B2 + t] = b2[t];
  }
  __syncthreads();

  {  // h = relu(ys @ w1 + b1) -> h[64][68]
    int r = t >> 2, jb = (t & 3) * 16;
    float hacc[16];
#pragma unroll
    for (int u = 0; u < 16; ++u) hacc[u] = sm[XS_B1 + jb + u];
#pragma unroll 4
    for (int c = 0; c < 32; ++c) {
      float yv = sm[XS_YS + r * 33 + c];
      const float4* wrow = reinterpret_cast<const float4*>(sm + XS_W1 + c * 64 + jb);
      float4 wq[4] = {wrow[0], wrow[1], wrow[2], wrow[3]};
#pragma unroll
      for (int q = 0; q < 4; ++q)
#pragma unroll
        for (int u = 0; u < 4; ++u)
          hacc[q * 4 + u] = fmaf(yv, f4get(wq[q], u), hacc[q * 4 + u]);
    }
    float4* hrow = reinterpret_cast<float4*>(sm + XS_H + r * 68 + jb);
#pragma unroll
    for (int q = 0; q < 4; ++q)
      hrow[q] = make_float4(fmaxf(hacc[q * 4 + 0], 0.f), fmaxf(hacc[q * 4 + 1], 0.f),
                            fmaxf(hacc[q * 4 + 2], 0.f), fmaxf(hacc[q * 4 + 3], 0.f));
  }
  __syncthreads();

  {  // out = h @ w2 + b2, store (overwrites this block's private column)
    int r = t >> 2, ob = (t & 3) * 8;
    float oacc[8];
#pragma unroll
    for (int u = 0; u < 8; ++u) oacc[u] = sm[XS_B2 + ob + u];
#pragma unroll 8
    for (int j = 0; j < 64; ++j) {
      float hv = sm[XS_H + r * 68 + j];
      const float4* w2r = reinterpret_cast<const float4*>(sm + XS_W2 + j * 32 + ob);
      float4 wa = w2r[0], wb = w2r[1];
#pragma unroll
      for (int u = 0; u < 4; ++u) oacc[u] = fmaf(hv, f4get(wa, u), oacc[u]);
#pragma unroll
      for (int u = 0; u < 4; ++u) oacc[4 + u] = fmaf(hv, f4get(wb, u), oacc[4 + u]);
    }
    float* op = out + gbase + (size_t)r * RSTR + ob;
    *reinterpret_cast<float4*>(op) = make_float4(oacc[0], oacc[1], oacc[2], oacc[3]);
    *reinterpret_cast<float4*>(op + 4) = make_float4(oacc[4], oacc[5], oacc[6], oacc[7]);
  }
}

}  // namespace

extern "C" void kernel_launch(void* const* d_in, const int* in_sizes, int n_in,
                              void* d_out, int out_size, void* d_ws, size_t ws_size,
                              hipStream_t stream) {
  const float* x  = (const float*)d_in[0];
  const float* wx = (const float*)d_in[1];
  const float* wz = (const float*)d_in[2];
  const float* w1 = (const float*)d_in[3];
  const float* b1 = (const float*)d_in[4];
  const float* w2 = (const float*)d_in[5];
  const float* b2 = (const float*)d_in[6];
  float* out = (float*)d_out;

  hipLaunchKernelGGL(kz, dim3(NBLK), dim3(256), 0, stream, x, wz, out);
  hipLaunchKernelGGL(kx, dim3(NBLK), dim3(256), 0, stream, x, wx, w1, b1, w2, b2, out);
}

// Round 2
// 508.402 us; speedup vs baseline: 2.0274x; 2.0274x over previous
//
#include <hip/hip_runtime.h>

namespace {

constexpr size_t RSTR = 64 * 64 * 32;   // s1 stride in floats

// ---- workspace layout (floats) ----
constexpr int WS_TF = 0;     // fwd trig  [z][m2] float4, 512 entries  (2048 floats)
constexpr int WS_TI = 2048;  // inv trig  [z][m]  float2, 1024 entries (2048 floats)

// Build trig tables once per launch. Folds rfft/irfft 'ortho' norms (1/8 each)
// and irfft hermitian handling (Im(DC) dropped -> sc0=1/8, m>=1 -> 1/4).
__global__ __launch_bounds__(256) void kinit(float* __restrict__ ws) {
  const int t = threadIdx.x;
  for (int e = t; e < 512; e += 256) {
    int z = e >> 3, m2 = e & 7;
    float s0, c0, s1, c1;
    sincospif((float)((2 * m2) * z) * (1.0f / 32.0f), &s0, &c0);
    sincospif((float)((2 * m2 + 1) * z) * (1.0f / 32.0f), &s1, &c1);
    reinterpret_cast<float4*>(ws + WS_TF)[e] =
        make_float4(0.125f * c0, -0.125f * s0, 0.125f * c1, -0.125f * s1);
  }
  for (int e = t; e < 1024; e += 256) {
    int z = e >> 4, m = e & 15;
    float s, c;
    sincospif((float)(m * z) * (1.0f / 32.0f), &s, &c);
    float sc = (m == 0) ? 0.125f : 0.25f;
    reinterpret_cast<float2*>(ws + WS_TI)[e] = make_float2(sc * c, -sc * s);
  }
}

// ---------------- phase helpers (shared by kz/kx) ----------------

// forward: F[m][i] = sum_z x[z][i] * E[m][z]; x fetched via lambda-ish ptr math.
// thread map: i = t&31, m2 = t>>5 (owns modes 2*m2, 2*m2+1). XOR-swizzled F.
template <bool STRIDED>
__device__ __forceinline__ void phase_forward(const float* __restrict__ x, size_t gb0,
                                              const float* __restrict__ ws,
                                              float2* __restrict__ F2, int t) {
  const int i = t & 31, m2 = t >> 5;
  const float4* tf = reinterpret_cast<const float4*>(ws + WS_TF);
  float re0[2] = {0.f, 0.f}, im0[2] = {0.f, 0.f};
  float re1[2] = {0.f, 0.f}, im1[2] = {0.f, 0.f};
#pragma unroll 4
  for (int z = 0; z < 64; ++z) {
    float4 tv = tf[z * 8 + m2];
#pragma unroll
    for (int c = 0; c < 2; ++c) {
      float xv = STRIDED ? x[gb0 + (size_t)c * 32 + (size_t)z * RSTR + i]
                         : x[gb0 + (size_t)c * 2048 + z * 32 + i];
      re0[c] = fmaf(xv, tv.x, re0[c]);
      im0[c] = fmaf(xv, tv.y, im0[c]);
      re1[c] = fmaf(xv, tv.z, re1[c]);
      im1[c] = fmaf(xv, tv.w, im1[c]);
    }
  }
  const int m0 = 2 * m2, m1 = 2 * m2 + 1;
#pragma unroll
  for (int c = 0; c < 2; ++c) {
    F2[c * 512 + m0 * 32 + (i ^ m0)] = make_float2(re0[c], im0[c]);
    F2[c * 512 + m1 * 32 + (i ^ m1)] = make_float2(re1[c], im1[c]);
  }
}

// mix: P[m][o] = sum_i F[m][i] * W[i][o][m]; raw W layout [i][o][m][2].
// thread map: m = t&15, og = t>>4 (owns o = og, og+16). W reads 512B-coalesced.
__device__ __forceinline__ void phase_mix(const float2* __restrict__ F2,
                                          const float* __restrict__ wraw,
                                          float2* __restrict__ P2, int t) {
  const int m = t & 15, og = t >> 4;
  const float2* W2 = reinterpret_cast<const float2*>(wraw);
  float pr[2][2] = {{0.f, 0.f}, {0.f, 0.f}};
  float pi[2][2] = {{0.f, 0.f}, {0.f, 0.f}};
#pragma unroll 4
  for (int i = 0; i < 32; ++i) {
    float2 w0 = W2[(i * 32 + og) * 16 + m];
    float2 w1 = W2[(i * 32 + og + 16) * 16 + m];
#pragma unroll
    for (int c = 0; c < 2; ++c) {
      float2 f = F2[c * 512 + m * 32 + (i ^ m)];
      pr[c][0] = fmaf(f.x, w0.x, pr[c][0]); pr[c][0] = fmaf(f.y, -w0.y, pr[c][0]);
      pi[c][0] = fmaf(f.x, w0.y, pi[c][0]); pi[c][0] = fmaf(f.y,  w0.x, pi[c][0]);
      pr[c][1] = fmaf(f.x, w1.x, pr[c][1]); pr[c][1] = fmaf(f.y, -w1.y, pr[c][1]);
      pi[c][1] = fmaf(f.x, w1.y, pi[c][1]); pi[c][1] = fmaf(f.y,  w1.x, pi[c][1]);
    }
  }
#pragma unroll
  for (int c = 0; c < 2; ++c) {
    P2[c * 512 + m * 32 + (og ^ m)] = make_float2(pr[c][0], pi[c][0]);
    P2[c * 512 + m * 32 + ((og + 16) ^ m)] = make_float2(pr[c][1], pi[c][1]);
  }
}

// inverse: y[z][o] = sum_m Ti[z][m] . P[m][o]; two m-halves to bound VGPRs.
// thread map: o = t&31, z0 = t>>5 (owns z = z0+8k). acc pre-initialized by caller.
__device__ __forceinline__ void phase_inverse(const float2* __restrict__ P2,
                                              const float* __restrict__ ws,
                                              float acc[2][8], int t) {
  const int o = t & 31, z0 = t >> 5;
#pragma unroll
  for (int mh = 0; mh < 2; ++mh) {
    float2 pv[2][8];
#pragma unroll
    for (int c = 0; c < 2; ++c)
#pragma unroll
      for (int mm = 0; mm < 8; ++mm) {
        int m = mh * 8 + mm;
        pv[c][mm] = P2[c * 512 + m * 32 + (o ^ m)];
      }
#pragma unroll
    for (int k = 0; k < 8; ++k) {
      int z = z0 + 8 * k;
      const float4* tr = reinterpret_cast<const float4*>(ws + WS_TI + z * 32 + mh * 16);
      float4 t0 = tr[0], t1 = tr[1], t2 = tr[2], t3 = tr[3];
#pragma unroll
      for (int c = 0; c < 2; ++c) {
        float a = acc[c][k];
        a = fmaf(t0.x, pv[c][0].x, a); a = fmaf(t0.y, pv[c][0].y, a);
        a = fmaf(t0.z, pv[c][1].x, a); a = fmaf(t0.w, pv[c][1].y, a);
        a = fmaf(t1.x, pv[c][2].x, a); a = fmaf(t1.y, pv[c][2].y, a);
        a = fmaf(t1.z, pv[c][3].x, a); a = fmaf(t1.w, pv[c][3].y, a);
        a = fmaf(t2.x, pv[c][4].x, a); a = fmaf(t2.y, pv[c][4].y, a);
        a = fmaf(t2.z, pv[c][5].x, a); a = fmaf(t2.w, pv[c][5].y, a);
        a = fmaf(t3.x, pv[c][6].x, a); a = fmaf(t3.y, pv[c][6].y, a);
        a = fmaf(t3.z, pv[c][7].x, a); a = fmaf(t3.w, pv[c][7].y, a);
        acc[c][k] = a;
      }
    }
  }
}

// ---------------- z-branch: writes y_z into d_out ----------------
__global__ __launch_bounds__(256) void kz(const float* __restrict__ x,
                                          const float* __restrict__ wz,
                                          const float* __restrict__ ws,
                                          float* __restrict__ y) {
  __shared__ __align__(16) float sm[4096];   // 16 KB: F[2][512]f2 | P[2][512]f2
  const int t = threadIdx.x;
  const size_t base0 = (size_t)(2 * blockIdx.x) * 2048;
  float2* F2 = reinterpret_cast<float2*>(sm);
  float2* P2 = reinterpret_cast<float2*>(sm + 2048);

  phase_forward<false>(x, base0, ws, F2, t);
  __syncthreads();
  phase_mix(F2, wz, P2, t);
  __syncthreads();

  float acc[2][8];
#pragma unroll
  for (int c = 0; c < 2; ++c)
#pragma unroll
    for (int k = 0; k < 8; ++k) acc[c][k] = 0.f;
  phase_inverse(P2, ws, acc, t);

  const int o = t & 31, z0 = t >> 5;
#pragma unroll
  for (int c = 0; c < 2; ++c)
#pragma unroll
    for (int k = 0; k < 8; ++k)
      y[base0 + (size_t)c * 2048 + (z0 + 8 * k) * 32 + o] = acc[c][k];
}

// ------- x-branch + add z-partial + FFN; overwrites d_out -------
__global__ __launch_bounds__(256) void kx(const float* __restrict__ x,
                                          const float* __restrict__ wx,
                                          const float* __restrict__ w1g,
                                          const float* __restrict__ b1g,
                                          const float* __restrict__ w2g,
                                          const float* __restrict__ b2g,
                                          const float* __restrict__ ws,
                                          float* out) {
  __shared__ __align__(16) float sm[10240];  // 40960 B exactly -> 4 blocks/CU
  // regions: [0,2048) F -> w1 | [2048,4096) P -> w2 | [4096,8192) ys | [8192,10240) ht
  const int t = threadIdx.x;
  const int d = blockIdx.x;
  const int p = (d & 7) * 1024 + (d >> 3);   // XCD swizzle, bijective (8192 % 8 == 0)
  const int b = p >> 11, yy = (p >> 5) & 63, zz2 = (p & 31) * 2;
  const size_t gb0 = (size_t)b * 8388608 + (size_t)yy * 2048 + (size_t)zz2 * 32;

  float2* F2 = reinterpret_cast<float2*>(sm);
  float2* P2 = reinterpret_cast<float2*>(sm + 2048);
  float* ys = sm + 4096;   // [c][64][32] xor-swizzled
  float* ht = sm + 8192;   // [32][64]
  float* w1s = sm;         // overlays F after MIX
  float* w2s = sm + 2048;  // overlays P after INV

  phase_forward<true>(x, gb0, ws, F2, t);
  __syncthreads();
  phase_mix(F2, wx, P2, t);
  __syncthreads();

  {  // stage w1 (F region now dead) + inverse with z-partial init
    reinterpret_cast<float4*>(w1s)[t] = reinterpret_cast<const float4*>(w1g)[t];
    reinterpret_cast<float4*>(w1s)[t + 256] = reinterpret_cast<const float4*>(w1g)[t + 256];
    const int o = t & 31, z0 = t >> 5;
    float acc[2][8];
#pragma unroll
    for (int c = 0; c < 2; ++c)
#pragma unroll
      for (int k = 0; k < 8; ++k)
        acc[c][k] = out[gb0 + (size_t)c * 32 + (size_t)(z0 + 8 * k) * RSTR + o];
    phase_inverse(P2, ws, acc, t);
#pragma unroll
    for (int c = 0; c < 2; ++c)
#pragma unroll
      for (int k = 0; k < 8; ++k) {
        int z = z0 + 8 * k;
        ys[c * 2048 + z * 32 + (o ^ (z & 31))] = acc[c][k];
      }
  }
  __syncthreads();

  // ---- FFN: per col, two 32-hidden chunks through ht ----
  const int r = t & 63, g = t >> 6;
#pragma unroll
  for (int c = 0; c < 2; ++c) {
    float oacc[8];
#pragma unroll
    for (int u = 0; u < 8; ++u) oacc[u] = b2g[g * 8 + u];
    for (int jb0 = 0; jb0 < 64; jb0 += 32) {
      if (c == 0 && jb0 == 0) {  // stage w2 (P region dead after INV; sync below precedes OUT)
        reinterpret_cast<float4*>(w2s)[t] = reinterpret_cast<const float4*>(w2g)[t];
        reinterpret_cast<float4*>(w2s)[t + 256] = reinterpret_cast<const float4*>(w2g)[t + 256];
      }
      // H chunk: h[jb0+g*8 .. +7] for row r
      float hacc[8];
#pragma unroll
      for (int u = 0; u < 8; ++u) hacc[u] = b1g[jb0 + g * 8 + u];
#pragma unroll 4
      for (int cc = 0; cc < 32; ++cc) {
        float yv = ys[c * 2048 + r * 32 + (cc ^ (r & 31))];
        const float4* wrow = reinterpret_cast<const float4*>(w1s + cc * 64 + jb0 + g * 8);
        float4 wa = wrow[0], wb = wrow[1];
        hacc[0] = fmaf(yv, wa.x, hacc[0]); hacc[1] = fmaf(yv, wa.y, hacc[1]);
        hacc[2] = fmaf(yv, wa.z, hacc[2]); hacc[3] = fmaf(yv, wa.w, hacc[3]);
        hacc[4] = fmaf(yv, wb.x, hacc[4]); hacc[5] = fmaf(yv, wb.y, hacc[5]);
        hacc[6] = fmaf(yv, wb.z, hacc[6]); hacc[7] = fmaf(yv, wb.w, hacc[7]);
      }
#pragma unroll
      for (int u = 0; u < 8; ++u) ht[(g * 8 + u) * 64 + r] = fmaxf(hacc[u], 0.f);
      __syncthreads();
      // OUT chunk: accumulate into oacc
#pragma unroll 4
      for (int j = 0; j < 32; ++j) {
        float hv = ht[j * 64 + r];
        const float4* w2r = reinterpret_cast<const float4*>(w2s + (jb0 + j) * 32 + g * 8);
        float4 wa = w2r[0], wb = w2r[1];
        oacc[0] = fmaf(hv, wa.x, oacc[0]); oacc[1] = fmaf(hv, wa.y, oacc[1]);
        oacc[2] = fmaf(hv, wa.z, oacc[2]); oacc[3] = fmaf(hv, wa.w, oacc[3]);
        oacc[4] = fmaf(hv, wb.x, oacc[4]); oacc[5] = fmaf(hv, wb.y, oacc[5]);
        oacc[6] = fmaf(hv, wb.z, oacc[6]); oacc[7] = fmaf(hv, wb.w, oacc[7]);
      }
      __syncthreads();
    }
    float* op = out + gb0 + (size_t)c * 32 + (size_t)r * RSTR + g * 8;
    *reinterpret_cast<float4*>(op) = make_float4(oacc[0], oacc[1], oacc[2], oacc[3]);
    *reinterpret_cast<float4*>(op + 4) = make_float4(oacc[4], oacc[5], oacc[6], oacc[7]);
  }
}

}  // namespace

extern "C" void kernel_launch(void* const* d_in, const int* in_sizes, int n_in,
                              void* d_out, int out_size, void* d_ws, size_t ws_size,
                              hipStream_t stream) {
  const float* x  = (const float*)d_in[0];
  const float* wx = (const float*)d_in[1];
  const float* wz = (const float*)d_in[2];
  const float* w1 = (const float*)d_in[3];
  const float* b1 = (const float*)d_in[4];
  const float* w2 = (const float*)d_in[5];
  const float* b2 = (const float*)d_in[6];
  float* out = (float*)d_out;
  float* ws = (float*)d_ws;

  hipLaunchKernelGGL(kinit, dim3(1), dim3(256), 0, stream, ws);
  hipLaunchKernelGGL(kz, dim3(8192), dim3(256), 0, stream, x, wz, ws, out);
  hipLaunchKernelGGL(kx, dim3(8192), dim3(256), 0, stream, x, wx, w1, b1, w2, b2, ws, out);
}

// Round 3
// 146.055 us; speedup vs baseline: 7.0571x; 3.4809x over previous
//
#include <hip/hip_runtime.h>

namespace {

typedef _Float16 half_t;
typedef half_t f16x8 __attribute__((ext_vector_type(8)));
typedef float f32x4 __attribute__((ext_vector_type(4)));

constexpr size_t RSTR = 64 * 64 * 32;  // s1 stride in floats

// ---- ws layout (f16 element offsets), all arrays are [frag][lane][8] packed ----
constexpr int WS_TF = 0;       // forward Tf frags: 4  (mt*2+kt)
constexpr int WS_TI = 2048;    // inverse Ti frags: 4  (mt)
constexpr int WS_WZ = 4096;    // mix W' z-branch: 16 modes x 8 (kt*4+nt)
constexpr int WS_WX = 69632;   // mix W' x-branch
constexpr int WS_W1 = 135168;  // FFN w1 frags: 4 (nt)
constexpr int WS_W2 = 137216;  // FFN w2 frags: 4 (kt*2+nt)
// total 139264 f16 = 278528 bytes

__device__ __forceinline__ float f4get(const float4& v, int u) {
  return u == 0 ? v.x : (u == 1 ? v.y : (u == 2 ? v.z : v.w));
}

__device__ __forceinline__ f32x4 mfma16(f16x8 a, f16x8 b, f32x4 c) {
  return __builtin_amdgcn_mfma_f32_16x16x32_f16(a, b, c, 0, 0, 0);
}

// Pre-pack all shared MFMA operands into ws, fragment-ordered per lane.
// Fragment convention (consistent for A and B; contraction is k-permutation
// invariant as long as both sides use the same map):
//   lane l: r=l&15, g=l>>4; element e of K-tile kt -> k = kt*32 + 8*g + e
//   A[row=Mtile*16+r][k]; B[k][col=Ntile*16+r]
__global__ __launch_bounds__(256) void kinit(const float* __restrict__ wx,
                                             const float* __restrict__ wz,
                                             const float* __restrict__ w1,
                                             const float* __restrict__ w2,
                                             half_t* __restrict__ wsh) {
  const int id = blockIdx.x * 256 + threadIdx.x;
  const int l = id & 63, r = l & 15, g = l >> 4;
  f16x8 frag;
  if (id < 256) {  // Tf: [mc=2m+p][z], 1/8 norm, -sin folded
    int fid = id >> 6, mt = fid >> 1, kt = fid & 1;
#pragma unroll
    for (int e = 0; e < 8; ++e) {
      int k = kt * 32 + 8 * g + e;  // z
      int mc = mt * 16 + r, m = mc >> 1, p = mc & 1;
      float s, c;
      sincospif((float)(m * k) * (1.0f / 32.0f), &s, &c);
      frag[e] = (half_t)(0.125f * (p ? -s : c));
    }
    *(f16x8*)(wsh + WS_TF + (size_t)id * 8) = frag;
  } else if (id < 512) {  // Ti: [z'][k=2m+p], sc_0=1/8 else 1/4, (cos, -sin)
    int id2 = id - 256, mt = id2 >> 6;
#pragma unroll
    for (int e = 0; e < 8; ++e) {
      int zp = mt * 16 + r;
      int k = 8 * g + e, m = k >> 1, p = k & 1;
      float s, c;
      sincospif((float)(m * zp) * (1.0f / 32.0f), &s, &c);
      float sc = (m == 0) ? 0.125f : 0.25f;
      frag[e] = (half_t)(p ? -sc * s : sc * c);
    }
    *(f16x8*)(wsh + WS_TI + (size_t)id2 * 8) = frag;
  } else if (id < 16896) {  // W' realified: [k=2i+p][n=2o+q] per mode
    int id2 = id - 512;
    const float* wsrc = wz;
    size_t off = WS_WZ;
    if (id2 >= 8192) { id2 -= 8192; wsrc = wx; off = WS_WX; }
    int fid = id2 >> 6, m = fid >> 3, kt = (fid >> 2) & 1, nt = fid & 3;
#pragma unroll
    for (int e = 0; e < 8; ++e) {
      int k = kt * 32 + 8 * g + e, i = k >> 1, p = k & 1;
      int n = nt * 16 + r, o = n >> 1, q = n & 1;
      int base = ((i * 32 + o) * 16 + m) * 2;  // raw [i][o][mode][2]
      float re = wsrc[base], im = wsrc[base + 1];
      // q=0 (P_re): F_re*W_re + F_im*(-W_im); q=1 (P_im): F_re*W_im + F_im*W_re
      frag[e] = (half_t)(q ? (p ? re : im) : (p ? -im : re));
    }
    *(f16x8*)(wsh + off + (size_t)id2 * 8) = frag;
  } else if (id < 17152) {  // w1 [32 k][64 n]
    int id2 = id - 16896, nt = id2 >> 6;
#pragma unroll
    for (int e = 0; e < 8; ++e) {
      int k = 8 * g + e, n = nt * 16 + r;
      frag[e] = (half_t)w1[k * 64 + n];
    }
    *(f16x8*)(wsh + WS_W1 + (size_t)id2 * 8) = frag;
  } else if (id < 17408) {  // w2 [64 k][32 n]
    int id2 = id - 17152, fid = id2 >> 6, kt = fid >> 1, nt = fid & 1;
#pragma unroll
    for (int e = 0; e < 8; ++e) {
      int k = kt * 32 + 8 * g + e, n = nt * 16 + r;
      frag[e] = (half_t)w2[k * 32 + n];
    }
    *(f16x8*)(wsh + WS_W2 + (size_t)id2 * 8) = frag;
  }
}

// BR=0: z-branch (cols=(b,s1,s2), z=s3). Writes y_z f16 into out scratch slots.
// BR=1: x-branch (cols=(b,s2,s3), z=s1) + add y_z + FFN -> out fp32.
// y_z f16 for (col=(b,s1,s2), s3, o) lives at outh[col*4096 + s3*64 + o]:
// the first 64B of the 128B out-slot that the SAME kx block later overwrites.
template <int BR>
__global__ __launch_bounds__(256) void kspec(const float* __restrict__ x,
                                             const half_t* __restrict__ wsh,
                                             const float* __restrict__ b1g,
                                             const float* __restrict__ b2g,
                                             float* __restrict__ outf) {
  __shared__ __align__(16) char smraw[49152];
  half_t* XB = (half_t*)smraw;            // [256 rows=(c,i)][64 z] swz
  half_t* FB = (half_t*)smraw;            // [16 m][16 c][64 k=2i+p] swz
  half_t* PB = (half_t*)(smraw + 32768);  // [8 c][32 o][32 k=2m+p] swz
  half_t* YL = (half_t*)smraw;            // [512 rows=(c,z')][32 k=i] swz
  half_t* HL = (half_t*)(smraw + 32768);  // [128 rows][64 hid] swz
  half_t* outh = (half_t*)outf;
  const int t = threadIdx.x, l = t & 63, w = t >> 6, r = l & 15, g = l >> 4;
  const f32x4 vzero = {0.f, 0.f, 0.f, 0.f};

  const int col0 = blockIdx.x * 8;
  int b = 0, s2 = 0, s30 = 0;
  size_t xbase, zstr, cstr;
  if (BR == 0) {
    xbase = (size_t)col0 * 2048; zstr = 32; cstr = 2048;
  } else {
    b = col0 >> 12; s2 = (col0 >> 6) & 63; s30 = col0 & 63;
    xbase = (size_t)b * 8388608 + (size_t)s2 * 2048 + (size_t)s30 * 32;
    zstr = RSTR; cstr = 32;
  }

  // ---------------- stage x -> XB ----------------
  {
    int c = t >> 5, sub = t & 31;
    int i4 = (sub & 7) * 4, zq = sub >> 3;
    const float* xp = x + xbase + (size_t)c * cstr + i4;
#pragma unroll
    for (int zo = 0; zo < 2; ++zo) {
      int zb = zq * 16 + zo * 8;
      float4 v[8];
#pragma unroll
      for (int zz = 0; zz < 8; ++zz)
        v[zz] = *(const float4*)(xp + (size_t)(zb + zz) * zstr);
#pragma unroll
      for (int u = 0; u < 4; ++u) {
        f16x8 rowv;
#pragma unroll
        for (int zz = 0; zz < 8; ++zz) rowv[zz] = (half_t)f4get(v[zz], u);
        int rowi = c * 32 + i4 + u;
        int gr = (zb >> 3) ^ (rowi & 7);
        *(f16x8*)(XB + rowi * 64 + gr * 8) = rowv;
      }
    }
  }
  __syncthreads();

  // ---------------- forward: F[32 mc][256 (c,i)] = Tf @ X ----------------
  f32x4 fa[2][4];
#pragma unroll
  for (int mt = 0; mt < 2; ++mt)
#pragma unroll
    for (int nt = 0; nt < 4; ++nt) fa[mt][nt] = vzero;
  {
    f16x8 Atf[2][2], Bx[4][2];
#pragma unroll
    for (int mt = 0; mt < 2; ++mt)
#pragma unroll
      for (int kt = 0; kt < 2; ++kt)
        Atf[mt][kt] = *(const f16x8*)(wsh + WS_TF + (size_t)((mt * 2 + kt) * 64 + l) * 8);
#pragma unroll
    for (int nt = 0; nt < 4; ++nt)
#pragma unroll
      for (int kt = 0; kt < 2; ++kt) {
        int rowi = w * 64 + nt * 16 + r;
        int gr = (kt * 4 + g) ^ (rowi & 7);
        Bx[nt][kt] = *(const f16x8*)(XB + rowi * 64 + gr * 8);
      }
#pragma unroll
    for (int kt = 0; kt < 2; ++kt)
#pragma unroll
      for (int nt = 0; nt < 4; ++nt)
#pragma unroll
        for (int mt = 0; mt < 2; ++mt)
          fa[mt][nt] = mfma16(Atf[mt][kt], Bx[nt][kt], fa[mt][nt]);
  }
  __syncthreads();

  // ---------------- F unpack -> FB ----------------
#pragma unroll
  for (int mt = 0; mt < 2; ++mt)
#pragma unroll
    for (int nt = 0; nt < 4; ++nt)
#pragma unroll
      for (int q = 0; q < 4; ++q) {
        int mc = mt * 16 + 4 * g + q, m = mc >> 1, p = mc & 1;
        int n = w * 64 + nt * 16 + r, c = n >> 5, i = n & 31;
        int k = 2 * i + p;
        FB[(m * 16 + c) * 64 + ((k >> 3) ^ (c & 7)) * 8 + (k & 7)] = (half_t)fa[mt][nt][q];
      }
  __syncthreads();

  // ---------------- mix: P_m[16 c][64 (2o+q)] = F_m @ W'_m ----------------
  const half_t* WF = wsh + (BR == 0 ? WS_WZ : WS_WX);
#pragma unroll
  for (int j = 0; j < 4; ++j) {
    int m = w * 4 + j;
    f16x8 Af[2];
#pragma unroll
    for (int kt = 0; kt < 2; ++kt) {
      int gr = (kt * 4 + g) ^ (r & 7);
      Af[kt] = *(const f16x8*)(FB + (m * 16 + r) * 64 + gr * 8);
    }
    f32x4 pa[4];
#pragma unroll
    for (int nt = 0; nt < 4; ++nt) pa[nt] = vzero;
#pragma unroll
    for (int kt = 0; kt < 2; ++kt)
#pragma unroll
      for (int nt = 0; nt < 4; ++nt) {
        f16x8 Bw = *(const f16x8*)(WF + (size_t)((m * 8 + kt * 4 + nt) * 64 + l) * 8);
        pa[nt] = mfma16(Af[kt], Bw, pa[nt]);
      }
#pragma unroll
    for (int nt = 0; nt < 4; ++nt)
#pragma unroll
      for (int q = 0; q < 4; ++q) {
        int c = 4 * g + q;
        if (c < 8) {  // rows 8..15 are garbage (C=8), confined to D rows 8..15
          int n = nt * 16 + r, o = n >> 1, q2 = n & 1;
          int k = 2 * m + q2;
          PB[(c * 32 + o) * 32 + ((k >> 3) ^ (o & 3)) * 8 + (k & 7)] = (half_t)pa[nt][q];
        }
      }
  }
  __syncthreads();

  // ---------------- inverse: y_c[64 z'][32 o] = Ti @ P_c ----------------
  {
    f16x8 Ati[4];
#pragma unroll
    for (int mt = 0; mt < 4; ++mt)
      Ati[mt] = *(const f16x8*)(wsh + WS_TI + (size_t)(mt * 64 + l) * 8);
#pragma unroll
    for (int cc = 0; cc < 2; ++cc) {
      int c = w * 2 + cc;
      f16x8 Bp[2];
#pragma unroll
      for (int nt = 0; nt < 2; ++nt) {
        int o = nt * 16 + r;
        Bp[nt] = *(const f16x8*)(PB + (c * 32 + o) * 32 + (g ^ (o & 3)) * 8);
      }
      f32x4 ya[4][2];
#pragma unroll
      for (int mt = 0; mt < 4; ++mt)
#pragma unroll
        for (int nt = 0; nt < 2; ++nt) ya[mt][nt] = mfma16(Ati[mt], Bp[nt], vzero);
#pragma unroll
      for (int mt = 0; mt < 4; ++mt)
#pragma unroll
        for (int nt = 0; nt < 2; ++nt)
#pragma unroll
          for (int q = 0; q < 4; ++q) {
            int zp = mt * 16 + 4 * g + q, o = nt * 16 + r;
            if (BR == 0) {
              outh[(size_t)(col0 + c) * 4096 + zp * 64 + o] = (half_t)ya[mt][nt][q];
            } else {
              size_t kzcol = (size_t)(b * 64 + zp) * 64 + s2;
              float yz = (float)outh[kzcol * 4096 + (s30 + c) * 64 + o];
              float yv = ya[mt][nt][q] + yz;
              int rowi = c * 64 + zp;
              YL[rowi * 32 + ((o >> 3) ^ (rowi & 3)) * 8 + (o & 7)] = (half_t)yv;
            }
          }
    }
  }
  if (BR == 0) return;
  __syncthreads();

  // ---------------- FFN: 4 rounds of 128 rows through HL ----------------
  {
    f16x8 W1F[4], W2F[4];
#pragma unroll
    for (int nt = 0; nt < 4; ++nt)
      W1F[nt] = *(const f16x8*)(wsh + WS_W1 + (size_t)(nt * 64 + l) * 8);
#pragma unroll
    for (int f = 0; f < 4; ++f)
      W2F[f] = *(const f16x8*)(wsh + WS_W2 + (size_t)(f * 64 + l) * 8);
    float b1v[4], b2v[2];
#pragma unroll
    for (int nt = 0; nt < 4; ++nt) b1v[nt] = b1g[nt * 16 + r];
#pragma unroll
    for (int nt = 0; nt < 2; ++nt) b2v[nt] = b2g[nt * 16 + r];

    for (int rr = 0; rr < 4; ++rr) {
      f16x8 AY[2];
#pragma unroll
      for (int mt = 0; mt < 2; ++mt) {
        int rowi = rr * 128 + w * 32 + mt * 16 + r;
        AY[mt] = *(const f16x8*)(YL + rowi * 32 + (g ^ (rowi & 3)) * 8);
      }
      f32x4 ha[2][4];
#pragma unroll
      for (int mt = 0; mt < 2; ++mt)
#pragma unroll
        for (int nt = 0; nt < 4; ++nt) ha[mt][nt] = mfma16(AY[mt], W1F[nt], vzero);
#pragma unroll
      for (int mt = 0; mt < 2; ++mt)
#pragma unroll
        for (int nt = 0; nt < 4; ++nt)
#pragma unroll
          for (int q = 0; q < 4; ++q) {
            int rloc = w * 32 + mt * 16 + 4 * g + q, n = nt * 16 + r;
            float hv = fmaxf(ha[mt][nt][q] + b1v[nt], 0.f);
            HL[rloc * 64 + ((n >> 3) ^ (rloc & 7)) * 8 + (n & 7)] = (half_t)hv;
          }
      __syncthreads();
      f16x8 AH[2][2];
#pragma unroll
      for (int mt = 0; mt < 2; ++mt)
#pragma unroll
        for (int kt = 0; kt < 2; ++kt) {
          int rloc = w * 32 + mt * 16 + r;
          AH[mt][kt] = *(const f16x8*)(HL + rloc * 64 + ((kt * 4 + g) ^ (rloc & 7)) * 8);
        }
      f32x4 oa[2][2];
#pragma unroll
      for (int mt = 0; mt < 2; ++mt)
#pragma unroll
        for (int nt = 0; nt < 2; ++nt) oa[mt][nt] = vzero;
#pragma unroll
      for (int kt = 0; kt < 2; ++kt)
#pragma unroll
        for (int mt = 0; mt < 2; ++mt)
#pragma unroll
          for (int nt = 0; nt < 2; ++nt)
            oa[mt][nt] = mfma16(AH[mt][kt], W2F[kt * 2 + nt], oa[mt][nt]);
#pragma unroll
      for (int mt = 0; mt < 2; ++mt)
#pragma unroll
        for (int nt = 0; nt < 2; ++nt)
#pragma unroll
          for (int q = 0; q < 4; ++q) {
            int rowg = rr * 128 + w * 32 + mt * 16 + 4 * g + q;
            int c = rowg >> 6, zp = rowg & 63, o = nt * 16 + r;
            outf[(size_t)b * 8388608 + (size_t)zp * RSTR + (size_t)s2 * 2048 +
                 (size_t)(s30 + c) * 32 + o] = oa[mt][nt][q] + b2v[nt];
          }
      __syncthreads();
    }
  }
}

}  // namespace

extern "C" void kernel_launch(void* const* d_in, const int* in_sizes, int n_in,
                              void* d_out, int out_size, void* d_ws, size_t ws_size,
                              hipStream_t stream) {
  const float* x = (const float*)d_in[0];
  const float* wx = (const float*)d_in[1];
  const float* wz = (const float*)d_in[2];
  const float* w1 = (const float*)d_in[3];
  const float* b1 = (const float*)d_in[4];
  const float* w2 = (const float*)d_in[5];
  const float* b2 = (const float*)d_in[6];
  float* out = (float*)d_out;
  half_t* wsh = (half_t*)d_ws;

  hipLaunchKernelGGL(kinit, dim3(68), dim3(256), 0, stream, wx, wz, w1, w2, wsh);
  hipLaunchKernelGGL((kspec<0>), dim3(2048), dim3(256), 0, stream, x, wsh, b1, b2, out);
  hipLaunchKernelGGL((kspec<1>), dim3(2048), dim3(256), 0, stream, x, wsh, b1, b2, out);
}

// Round 4
// 135.452 us; speedup vs baseline: 7.6095x; 1.0783x over previous
//
#include <hip/hip_runtime.h>

namespace {

typedef _Float16 half_t;
typedef half_t f16x8 __attribute__((ext_vector_type(8)));
typedef float f32x4 __attribute__((ext_vector_type(4)));

constexpr size_t RSTR = 64 * 64 * 32;  // s1 stride in floats

// ---- ws layout (f16 element offsets), all arrays are [frag][lane][8] packed ----
constexpr int WS_TF = 0;       // forward Tf frags: 4  (mt*2+kt)
constexpr int WS_TI = 2048;    // inverse Ti frags: 4  (mt)
constexpr int WS_WZ = 4096;    // mix W' z-branch: 16 modes x 8 (kt*4+nt)
constexpr int WS_WX = 69632;   // mix W' x-branch
constexpr int WS_W1 = 135168;  // FFN w1 frags: 4 (nt)
constexpr int WS_W2 = 137216;  // FFN w2 frags: 4 (kt*2+nt)

__device__ __forceinline__ float f4get(const float4& v, int u) {
  return u == 0 ? v.x : (u == 1 ? v.y : (u == 2 ? v.z : v.w));
}

__device__ __forceinline__ f32x4 mfma16(f16x8 a, f16x8 b, f32x4 c) {
  return __builtin_amdgcn_mfma_f32_16x16x32_f16(a, b, c, 0, 0, 0);
}

// Pre-pack all shared MFMA operands into ws, fragment-ordered per lane.
//   lane l: r=l&15, g=l>>4; element e of K-tile kt -> k = kt*32 + 8*g + e
//   A[row=Mtile*16+r][k]; B[k][col=Ntile*16+r]
__global__ __launch_bounds__(256) void kinit(const float* __restrict__ wx,
                                             const float* __restrict__ wz,
                                             const float* __restrict__ w1,
                                             const float* __restrict__ w2,
                                             half_t* __restrict__ wsh) {
  const int id = blockIdx.x * 256 + threadIdx.x;
  const int l = id & 63, r = l & 15, g = l >> 4;
  f16x8 frag;
  if (id < 256) {  // Tf: [mc=2m+p][z], 1/8 norm, -sin folded
    int fid = id >> 6, mt = fid >> 1, kt = fid & 1;
#pragma unroll
    for (int e = 0; e < 8; ++e) {
      int k = kt * 32 + 8 * g + e;  // z
      int mc = mt * 16 + r, m = mc >> 1, p = mc & 1;
      float s, c;
      sincospif((float)(m * k) * (1.0f / 32.0f), &s, &c);
      frag[e] = (half_t)(0.125f * (p ? -s : c));
    }
    *(f16x8*)(wsh + WS_TF + (size_t)id * 8) = frag;
  } else if (id < 512) {  // Ti: [z'][k=2m+p], sc_0=1/8 else 1/4, (cos, -sin)
    int id2 = id - 256, mt = id2 >> 6;
#pragma unroll
    for (int e = 0; e < 8; ++e) {
      int zp = mt * 16 + r;
      int k = 8 * g + e, m = k >> 1, p = k & 1;
      float s, c;
      sincospif((float)(m * zp) * (1.0f / 32.0f), &s, &c);
      float sc = (m == 0) ? 0.125f : 0.25f;
      frag[e] = (half_t)(p ? -sc * s : sc * c);
    }
    *(f16x8*)(wsh + WS_TI + (size_t)id2 * 8) = frag;
  } else if (id < 16896) {  // W' realified: [k=2i+p][n=2o+q] per mode
    int id2 = id - 512;
    const float* wsrc = wz;
    size_t off = WS_WZ;
    if (id2 >= 8192) { id2 -= 8192; wsrc = wx; off = WS_WX; }
    int fid = id2 >> 6, m = fid >> 3, kt = (fid >> 2) & 1, nt = fid & 3;
#pragma unroll
    for (int e = 0; e < 8; ++e) {
      int k = kt * 32 + 8 * g + e, i = k >> 1, p = k & 1;
      int n = nt * 16 + r, o = n >> 1, q = n & 1;
      int base = ((i * 32 + o) * 16 + m) * 2;  // raw [i][o][mode][2]
      float re = wsrc[base], im = wsrc[base + 1];
      frag[e] = (half_t)(q ? (p ? re : im) : (p ? -im : re));
    }
    *(f16x8*)(wsh + off + (size_t)id2 * 8) = frag;
  } else if (id < 17152) {  // w1 [32 k][64 n]
    int id2 = id - 16896, nt = id2 >> 6;
#pragma unroll
    for (int e = 0; e < 8; ++e) {
      int k = 8 * g + e, n = nt * 16 + r;
      frag[e] = (half_t)w1[k * 64 + n];
    }
    *(f16x8*)(wsh + WS_W1 + (size_t)id2 * 8) = frag;
  } else if (id < 17408) {  // w2 [64 k][32 n]
    int id2 = id - 17152, fid = id2 >> 6, kt = fid >> 1, nt = fid & 1;
#pragma unroll
    for (int e = 0; e < 8; ++e) {
      int k = kt * 32 + 8 * g + e, n = nt * 16 + r;
      frag[e] = (half_t)w2[k * 32 + n];
    }
    *(f16x8*)(wsh + WS_W2 + (size_t)id2 * 8) = frag;
  }
}

// ============== z-branch (unchanged from round 2, proven ~BW-bound) ==============
template <int BR>
__global__ __launch_bounds__(256) void kspec(const float* __restrict__ x,
                                             const half_t* __restrict__ wsh,
                                             const float* __restrict__ b1g,
                                             const float* __restrict__ b2g,
                                             float* __restrict__ outf) {
  __shared__ __align__(16) char smraw[49152];
  half_t* XB = (half_t*)smraw;            // [256 rows=(c,i)][64 z] swz
  half_t* FB = (half_t*)smraw;            // [16 m][16 c][64 k=2i+p] swz
  half_t* PB = (half_t*)(smraw + 32768);  // [8 c][32 o][32 k=2m+p] swz
  half_t* outh = (half_t*)outf;
  const int t = threadIdx.x, l = t & 63, w = t >> 6, r = l & 15, g = l >> 4;
  const f32x4 vzero = {0.f, 0.f, 0.f, 0.f};

  const int col0 = blockIdx.x * 8;
  size_t xbase = (size_t)col0 * 2048, zstr = 32, cstr = 2048;

  {  // stage x -> XB
    int c = t >> 5, sub = t & 31;
    int i4 = (sub & 7) * 4, zq = sub >> 3;
    const float* xp = x + xbase + (size_t)c * cstr + i4;
#pragma unroll
    for (int zo = 0; zo < 2; ++zo) {
      int zb = zq * 16 + zo * 8;
      float4 v[8];
#pragma unroll
      for (int zz = 0; zz < 8; ++zz)
        v[zz] = *(const float4*)(xp + (size_t)(zb + zz) * zstr);
#pragma unroll
      for (int u = 0; u < 4; ++u) {
        f16x8 rowv;
#pragma unroll
        for (int zz = 0; zz < 8; ++zz) rowv[zz] = (half_t)f4get(v[zz], u);
        int rowi = c * 32 + i4 + u;
        int gr = (zb >> 3) ^ (rowi & 7);
        *(f16x8*)(XB + rowi * 64 + gr * 8) = rowv;
      }
    }
  }
  __syncthreads();

  // forward
  f32x4 fa[2][4];
#pragma unroll
  for (int mt = 0; mt < 2; ++mt)
#pragma unroll
    for (int nt = 0; nt < 4; ++nt) fa[mt][nt] = vzero;
  {
    f16x8 Atf[2][2], Bx[4][2];
#pragma unroll
    for (int mt = 0; mt < 2; ++mt)
#pragma unroll
      for (int kt = 0; kt < 2; ++kt)
        Atf[mt][kt] = *(const f16x8*)(wsh + WS_TF + (size_t)((mt * 2 + kt) * 64 + l) * 8);
#pragma unroll
    for (int nt = 0; nt < 4; ++nt)
#pragma unroll
      for (int kt = 0; kt < 2; ++kt) {
        int rowi = w * 64 + nt * 16 + r;
        int gr = (kt * 4 + g) ^ (rowi & 7);
        Bx[nt][kt] = *(const f16x8*)(XB + rowi * 64 + gr * 8);
      }
#pragma unroll
    for (int kt = 0; kt < 2; ++kt)
#pragma unroll
      for (int nt = 0; nt < 4; ++nt)
#pragma unroll
        for (int mt = 0; mt < 2; ++mt)
          fa[mt][nt] = mfma16(Atf[mt][kt], Bx[nt][kt], fa[mt][nt]);
  }
  __syncthreads();

#pragma unroll
  for (int mt = 0; mt < 2; ++mt)
#pragma unroll
    for (int nt = 0; nt < 4; ++nt)
#pragma unroll
      for (int q = 0; q < 4; ++q) {
        int mc = mt * 16 + 4 * g + q, m = mc >> 1, p = mc & 1;
        int n = w * 64 + nt * 16 + r, c = n >> 5, i = n & 31;
        int k = 2 * i + p;
        FB[(m * 16 + c) * 64 + ((k >> 3) ^ (c & 7)) * 8 + (k & 7)] = (half_t)fa[mt][nt][q];
      }
  __syncthreads();

  // mix
  const half_t* WF = wsh + WS_WZ;
#pragma unroll
  for (int j = 0; j < 4; ++j) {
    int m = w * 4 + j;
    f16x8 Af[2];
#pragma unroll
    for (int kt = 0; kt < 2; ++kt) {
      int gr = (kt * 4 + g) ^ (r & 7);
      Af[kt] = *(const f16x8*)(FB + (m * 16 + r) * 64 + gr * 8);
    }
    f32x4 pa[4];
#pragma unroll
    for (int nt = 0; nt < 4; ++nt) pa[nt] = vzero;
#pragma unroll
    for (int kt = 0; kt < 2; ++kt)
#pragma unroll
      for (int nt = 0; nt < 4; ++nt) {
        f16x8 Bw = *(const f16x8*)(WF + (size_t)((m * 8 + kt * 4 + nt) * 64 + l) * 8);
        pa[nt] = mfma16(Af[kt], Bw, pa[nt]);
      }
#pragma unroll
    for (int nt = 0; nt < 4; ++nt)
#pragma unroll
      for (int q = 0; q < 4; ++q) {
        int c = 4 * g + q;
        if (c < 8) {
          int n = nt * 16 + r, o = n >> 1, q2 = n & 1;
          int k = 2 * m + q2;
          PB[(c * 32 + o) * 32 + ((k >> 3) ^ (o & 3)) * 8 + (k & 7)] = (half_t)pa[nt][q];
        }
      }
  }
  __syncthreads();

  // inverse + store y_z f16 into out scratch slots
  {
    f16x8 Ati[4];
#pragma unroll
    for (int mt = 0; mt < 4; ++mt)
      Ati[mt] = *(const f16x8*)(wsh + WS_TI + (size_t)(mt * 64 + l) * 8);
#pragma unroll
    for (int cc = 0; cc < 2; ++cc) {
      int c = w * 2 + cc;
      f16x8 Bp[2];
#pragma unroll
      for (int nt = 0; nt < 2; ++nt) {
        int o = nt * 16 + r;
        Bp[nt] = *(const f16x8*)(PB + (c * 32 + o) * 32 + (g ^ (o & 3)) * 8);
      }
      f32x4 ya[4][2];
#pragma unroll
      for (int mt = 0; mt < 4; ++mt)
#pragma unroll
        for (int nt = 0; nt < 2; ++nt) ya[mt][nt] = mfma16(Ati[mt], Bp[nt], vzero);
#pragma unroll
      for (int mt = 0; mt < 4; ++mt)
#pragma unroll
        for (int nt = 0; nt < 2; ++nt)
#pragma unroll
          for (int q = 0; q < 4; ++q) {
            int zp = mt * 16 + 4 * g + q, o = nt * 16 + r;
            outh[(size_t)(col0 + c) * 4096 + zp * 64 + o] = (half_t)ya[mt][nt][q];
          }
    }
  }
}

// ============== x-branch + add y_z + FFN (C=4, 32KB LDS, 5 blocks/CU) ==============
__global__ __launch_bounds__(256, 5) void kx4(const float* __restrict__ x,
                                              const half_t* __restrict__ wsh,
                                              const float* __restrict__ b1g,
                                              const float* __restrict__ b2g,
                                              float* __restrict__ outf) {
  __shared__ __align__(16) half_t smh[16384];  // 32 KB
  half_t* XB = smh;            // [128 rows=(c*32+i)][64 z]    16KB  [0,8192)
  half_t* FB = smh + 8192;     // [16 m][4 c][64 k=2i+p]        8KB  [8192,12288)
  half_t* PB = smh + 12288;    // [4 c][32 o][32 k=2m+p]        8KB  [12288,16384)
  half_t* YL = smh;            // [256 rows=(c*64+z')][32 o]   16KB  overlays XB (dead)
  half_t* HL = smh + 8192;     // [64 rows][64 n]               8KB  overlays FB (dead)
  half_t* outh = (half_t*)outf;
  const int t = threadIdx.x, l = t & 63, w = t >> 6, r = l & 15, g = l >> 4;
  const f32x4 vzero = {0.f, 0.f, 0.f, 0.f};

  const int d = blockIdx.x;
  const int p = (d & 7) * 512 + (d >> 3);  // XCD-bijective swizzle (4096 = 8*512)
  const int col0 = p * 4;
  const int b = col0 >> 12, s2 = (col0 >> 6) & 63, s30 = col0 & 63;
  const size_t xbase = (size_t)b * 8388608 + (size_t)s2 * 2048 + (size_t)s30 * 32;

  {  // ---- stage x -> XB (rows = c*32+i, cols = z = s1) ----
    int sub = t & 31, zq = t >> 5;          // zq in [0,8): granule index
    int c = sub >> 3, i4 = (sub & 7) * 4;
    const float* xp = x + xbase + (size_t)c * 32 + i4 + (size_t)(zq * 8) * RSTR;
    float4 v[8];
#pragma unroll
    for (int zz = 0; zz < 8; ++zz) v[zz] = *(const float4*)(xp + (size_t)zz * RSTR);
#pragma unroll
    for (int uu = 0; uu < 4; ++uu) {
      int u = (uu + sub) & 3;               // lane-rotated to spread banks
      f16x8 rowv;
#pragma unroll
      for (int zz = 0; zz < 8; ++zz) rowv[zz] = (half_t)f4get(v[zz], u);
      int rowi = c * 32 + i4 + u;
      *(f16x8*)(XB + rowi * 64 + (zq ^ (rowi & 7)) * 8) = rowv;
    }
  }
  __syncthreads();

  // ---- forward: F[32 mc][128 n=(c,i)] = Tf @ X ----
  f32x4 fa[2][2];
  {
    f16x8 Atf[2][2], Bx[2][2];
#pragma unroll
    for (int mt = 0; mt < 2; ++mt)
#pragma unroll
      for (int kt = 0; kt < 2; ++kt)
        Atf[mt][kt] = *(const f16x8*)(wsh + WS_TF + (size_t)((mt * 2 + kt) * 64 + l) * 8);
#pragma unroll
    for (int nt = 0; nt < 2; ++nt)
#pragma unroll
      for (int kt = 0; kt < 2; ++kt) {
        int rowi = w * 32 + nt * 16 + r;
        Bx[nt][kt] = *(const f16x8*)(XB + rowi * 64 + (((kt * 4 + g) ^ (rowi & 7))) * 8);
      }
#pragma unroll
    for (int mt = 0; mt < 2; ++mt)
#pragma unroll
      for (int nt = 0; nt < 2; ++nt) fa[mt][nt] = vzero;
#pragma unroll
    for (int kt = 0; kt < 2; ++kt)
#pragma unroll
      for (int nt = 0; nt < 2; ++nt)
#pragma unroll
        for (int mt = 0; mt < 2; ++mt)
          fa[mt][nt] = mfma16(Atf[mt][kt], Bx[nt][kt], fa[mt][nt]);
  }
  // FB region is disjoint from XB: no barrier needed before writing
#pragma unroll
  for (int mt = 0; mt < 2; ++mt)
#pragma unroll
    for (int nt = 0; nt < 2; ++nt)
#pragma unroll
      for (int q = 0; q < 4; ++q) {
        int mc = mt * 16 + 4 * g + q, m = mc >> 1, pp = mc & 1;
        int n = w * 32 + nt * 16 + r, c = n >> 5, i = n & 31;
        int k = 2 * i + pp;
        FB[(m * 4 + c) * 64 + (((k >> 3) ^ ((m + 2 * c) & 7))) * 8 + (k & 7)] =
            (half_t)fa[mt][nt][q];
      }
  __syncthreads();

  // ---- mix: P_m[c][64 (2o+q)] = F_m @ W'_m; A rows r -> F[m][r&3] (bcast) ----
#pragma unroll
  for (int j = 0; j < 4; ++j) {
    int m = w * 4 + j;
    int rsel = r & 3, keym = (m + 2 * rsel) & 7;
    f16x8 Af[2];
#pragma unroll
    for (int kt = 0; kt < 2; ++kt)
      Af[kt] = *(const f16x8*)(FB + (m * 4 + rsel) * 64 + (((kt * 4 + g) ^ keym)) * 8);
    f32x4 pa[4];
#pragma unroll
    for (int nt = 0; nt < 4; ++nt) pa[nt] = vzero;
#pragma unroll
    for (int kt = 0; kt < 2; ++kt)
#pragma unroll
      for (int nt = 0; nt < 4; ++nt) {
        f16x8 Bw = *(const f16x8*)(wsh + WS_WX + (size_t)((m * 8 + kt * 4 + nt) * 64 + l) * 8);
        pa[nt] = mfma16(Af[kt], Bw, pa[nt]);
      }
    if (g == 0) {  // D rows 0..3 = c
#pragma unroll
      for (int nt = 0; nt < 4; ++nt)
#pragma unroll
        for (int q = 0; q < 4; ++q) {
          int c = q;
          int n = nt * 16 + r, o = n >> 1, q2 = n & 1;
          int k = 2 * m + q2;
          PB[(c * 32 + o) * 32 + (((k >> 3) ^ (o & 3))) * 8 + (k & 7)] = (half_t)pa[nt][q];
        }
    }
  }
  __syncthreads();

  // ---- inverse (c = w): y = Ti @ P_c + y_z -> YL ----
  {
    // prefetch y_z for this thread (32 f16), hidden under ds reads + MFMAs
    half_t yzr[4][2][4];
    const half_t* yzp = outh + ((size_t)b * 4096 + s2) * 4096 + (size_t)(s30 + w) * 64 +
                        (size_t)(4 * g) * 262144 + r;
#pragma unroll
    for (int mt = 0; mt < 4; ++mt)
#pragma unroll
      for (int q = 0; q < 4; ++q)
#pragma unroll
        for (int nt = 0; nt < 2; ++nt)
          yzr[mt][nt][q] = yzp[(size_t)(mt * 16 + q) * 262144 + nt * 16];

    f16x8 Ati[4], Bp[2];
#pragma unroll
    for (int mt = 0; mt < 4; ++mt)
      Ati[mt] = *(const f16x8*)(wsh + WS_TI + (size_t)(mt * 64 + l) * 8);
#pragma unroll
    for (int nt = 0; nt < 2; ++nt) {
      int o = nt * 16 + r;
      Bp[nt] = *(const f16x8*)(PB + (w * 32 + o) * 32 + ((g ^ (o & 3))) * 8);
    }
    f32x4 ya[4][2];
#pragma unroll
    for (int mt = 0; mt < 4; ++mt)
#pragma unroll
      for (int nt = 0; nt < 2; ++nt) ya[mt][nt] = mfma16(Ati[mt], Bp[nt], vzero);
#pragma unroll
    for (int mt = 0; mt < 4; ++mt)
#pragma unroll
      for (int nt = 0; nt < 2; ++nt)
#pragma unroll
        for (int q = 0; q < 4; ++q) {
          int zp = mt * 16 + 4 * g + q, o = nt * 16 + r;
          float acc = ya[mt][nt][q] + (float)yzr[mt][nt][q];
          int rowi = w * 64 + zp;
          YL[rowi * 32 + (((o >> 3) ^ ((rowi >> 2) & 3))) * 8 + (o & 7)] = (half_t)acc;
        }
  }
  __syncthreads();

  // ---- FFN: 4 rounds of 64 rows (= one s3 column per round) ----
  {
    f16x8 W1F[4], W2F[4];
#pragma unroll
    for (int nt = 0; nt < 4; ++nt)
      W1F[nt] = *(const f16x8*)(wsh + WS_W1 + (size_t)(nt * 64 + l) * 8);
#pragma unroll
    for (int f = 0; f < 4; ++f)
      W2F[f] = *(const f16x8*)(wsh + WS_W2 + (size_t)(f * 64 + l) * 8);
    float b1v[4], b2v[2];
#pragma unroll
    for (int nt = 0; nt < 4; ++nt) b1v[nt] = b1g[nt * 16 + r];
#pragma unroll
    for (int nt = 0; nt < 2; ++nt) b2v[nt] = b2g[nt * 16 + r];

    for (int rr = 0; rr < 4; ++rr) {
      int rowA = rr * 64 + w * 16 + r;
      f16x8 AY = *(const f16x8*)(YL + rowA * 32 + ((g ^ ((rowA >> 2) & 3))) * 8);
      f32x4 ha[4];
#pragma unroll
      for (int nt = 0; nt < 4; ++nt) ha[nt] = mfma16(AY, W1F[nt], vzero);
#pragma unroll
      for (int nt = 0; nt < 4; ++nt)
#pragma unroll
        for (int q = 0; q < 4; ++q) {
          int rloc = w * 16 + 4 * g + q, n = nt * 16 + r;
          float hv = fmaxf(ha[nt][q] + b1v[nt], 0.f);
          HL[rloc * 64 + (((n >> 3) ^ ((rloc >> 2) & 7))) * 8 + (n & 7)] = (half_t)hv;
        }
      __syncthreads();
      int rowA2 = w * 16 + r;
      f16x8 AH[2];
#pragma unroll
      for (int kt = 0; kt < 2; ++kt)
        AH[kt] = *(const f16x8*)(HL + rowA2 * 64 + (((kt * 4 + g) ^ ((rowA2 >> 2) & 7))) * 8);
      f32x4 oa[2];
#pragma unroll
      for (int nt = 0; nt < 2; ++nt) oa[nt] = vzero;
#pragma unroll
      for (int kt = 0; kt < 2; ++kt)
#pragma unroll
        for (int nt = 0; nt < 2; ++nt) oa[nt] = mfma16(AH[kt], W2F[kt * 2 + nt], oa[nt]);
#pragma unroll
      for (int nt = 0; nt < 2; ++nt)
#pragma unroll
        for (int q = 0; q < 4; ++q) {
          int zp2 = w * 16 + 4 * g + q, o = nt * 16 + r;
          outf[(size_t)b * 8388608 + (size_t)zp2 * RSTR + (size_t)s2 * 2048 +
               (size_t)(s30 + rr) * 32 + o] = oa[nt][q] + b2v[nt];
        }
      if (rr < 3) __syncthreads();
    }
  }
}

}  // namespace

extern "C" void kernel_launch(void* const* d_in, const int* in_sizes, int n_in,
                              void* d_out, int out_size, void* d_ws, size_t ws_size,
                              hipStream_t stream) {
  const float* x = (const float*)d_in[0];
  const float* wx = (const float*)d_in[1];
  const float* wz = (const float*)d_in[2];
  const float* w1 = (const float*)d_in[3];
  const float* b1 = (const float*)d_in[4];
  const float* w2 = (const float*)d_in[5];
  const float* b2 = (const float*)d_in[6];
  float* out = (float*)d_out;
  half_t* wsh = (half_t*)d_ws;

  hipLaunchKernelGGL(kinit, dim3(68), dim3(256), 0, stream, wx, wz, w1, w2, wsh);
  hipLaunchKernelGGL((kspec<0>), dim3(2048), dim3(256), 0, stream, x, wsh, b1, b2, out);
  hipLaunchKernelGGL(kx4, dim3(4096), dim3(256), 0, stream, x, wsh, b1, b2, out);
}